// Round 10
// baseline (568.969 us; speedup 1.0000x reference)
//
#include <hip/hip_runtime.h>
#include <math.h>

// Problem constants: x(256,8192) b,q,e(8192) M(100,8192) out(256,100)
#define NN 8192
#define BB 256
#define CC 100
#define MAX_ITERS 4096

// Flavor (G): the reference evidently computes the skew-tent map as
//   m' = num * r,  r = hoisted IEEE-correctly-rounded f32 reciprocal
//        (rb = 1.0f/b, rob = 1.0f/(1-b), computed once per column)
// -- the classic vectorized/hoisted transliteration of the torch loop.
// This flavor has absorption traps (num*r rounds to exactly 1.0 ->
// (1-1)*rob = 0 -> fixed point -> k caps at 4097); r8/r9 (hw v_rcp_f32,
// which bit-agrees with the IEEE reciprocal on most columns) matched the
// trap set exactly and left only a ~0.035 residual on the disagreeing
// columns. Native f32 division on gfx950 is IEEE correctly rounded
// (established r1/r2 == r6), so 1.0f/b here reproduces the reference's
// reciprocals bit-for-bit; the per-iteration multiply is a plain
// v_mul_f32 (no FMA contraction possible: no adds).
__global__ __launch_bounds__(256) void gls_fused_kernel(
    const float* __restrict__ x, const float* __restrict__ bmap,
    const float* __restrict__ qini, const float* __restrict__ eps,
    const float* __restrict__ M, float* __restrict__ out)
{
    __shared__ float k_lds[NN];   // 32 KB: this row's firing pattern (k <= 4097, exact)
    __shared__ double redsh[4];

    const int i   = blockIdx.x;   // sample row
    const int tid = threadIdx.x;
    const int wid = tid >> 6, lane = tid & 63;

    // ---------------- Phase 1: fire neurons for row i ----------------
    double sumsq = 0.0;
    for (int s = 0; s < 32; ++s) {
        const int j = tid + 256 * s;
        const float bv = bmap[j];
        const float qv = qini[j];
        const float ev = eps[j];
        const float xv = x[(size_t)i * NN + j];
        const float lov = xv - ev;          // exact f32 sub, same bits as ref
        const float hiv = xv + ev;
        const float obv = 1.0f - bv;        // exact (Sterbenz)
        const float rb  = 1.0f / bv;        // IEEE f32 reciprocal, hoisted
        const float rob = 1.0f / obv;       // IEEE f32 reciprocal, hoisted

        float m  = qv;
        float kk = 1.0f;
        bool  a  = (qv != 0.0f);            // q==0 never fires
        for (int it = 0; a && it < MAX_ITERS; ++it) {
            const bool  lt  = (m < bv);
            const float num = lt ? m  : (1.0f - m);
            const float r   = lt ? rb : rob;
            m = num * r;                    // reciprocal-multiply division flavor
            a = (m < lov) || (m > hiv);
            kk += a ? 1.0f : 0.0f;
        }
        k_lds[j] = kk;
        sumsq += (double)kk * (double)kk;
    }

    // block-reduce sum(k^2) -> row norm
    #pragma unroll
    for (int off = 32; off; off >>= 1) sumsq += __shfl_down(sumsq, off, 64);
    if (lane == 0) redsh[wid] = sumsq;
    __syncthreads();                        // also fences k_lds for phase 2
    const double rn = fmax(sqrt(redsh[0] + redsh[1] + redsh[2] + redsh[3]), 1e-8);

    // ---------------- Phase 2: cosine logits vs 100 classes (f64 accum) ----------------
    for (int cc2 = 0; cc2 < 25; ++cc2) {
        const int c = wid * 25 + cc2;
        const float4* Mp = (const float4*)(M + (size_t)c * NN);
        double dot = 0.0, msq = 0.0;
        #pragma unroll 4
        for (int s = 0; s < 32; ++s) {
            const float4 mv = Mp[lane + 64 * s];
            const float4 kv = *(const float4*)(&k_lds[4 * (lane + 64 * s)]);
            dot += (double)kv.x * (double)mv.x + (double)kv.y * (double)mv.y
                 + (double)kv.z * (double)mv.z + (double)kv.w * (double)mv.w;
            msq += (double)mv.x * (double)mv.x + (double)mv.y * (double)mv.y
                 + (double)mv.z * (double)mv.z + (double)mv.w * (double)mv.w;
        }
        #pragma unroll
        for (int off = 32; off; off >>= 1) {
            dot += __shfl_down(dot, off, 64);
            msq += __shfl_down(msq, off, 64);
        }
        if (lane == 0) {
            const double mn = fmax(sqrt(msq), 1e-8);
            out[(size_t)i * CC + c] = (float)(dot / (rn * mn));
        }
    }
}

// ---------------------------------------------------------------------------
extern "C" void kernel_launch(void* const* d_in, const int* in_sizes, int n_in,
                              void* d_out, int out_size, void* d_ws, size_t ws_size,
                              hipStream_t stream) {
    const float* x = (const float*)d_in[0];  // (256, 8192)
    const float* b = (const float*)d_in[1];  // (8192,)
    const float* q = (const float*)d_in[2];  // (8192,)
    const float* e = (const float*)d_in[3];  // (8192,)
    const float* M = (const float*)d_in[4];  // (100, 8192)
    float* out = (float*)d_out;              // (256, 100)

    (void)d_ws; (void)ws_size;               // zero-workspace design
    gls_fused_kernel<<<dim3(BB), dim3(256), 0, stream>>>(x, b, q, e, M, out);
}

// Round 11
// 329.152 us; speedup vs baseline: 1.7286x; 1.7286x over previous
//
#include <hip/hip_runtime.h>
#include <math.h>

// Problem constants: x(256,8192) b,q,e(8192) M(100,8192) out(256,100)
#define NN 8192
#define BB 256
#define CC 100
#define MAX_ITERS 4096
#define RPT 8   // rows per thread in fire kernel

// ===========================================================================
// FAST PATH (ws_size >= k matrix + norms)
// ===========================================================================

// ---------------------------------------------------------------------------
// Fire kernel: thread = (column j, 8-row group). The map trajectory depends
// only on the column (q_j, b_j), so one reciprocal-multiply map step is
// shared by 8 band-checks. Locked reference flavor: hoisted IEEE f32
// reciprocals rb=1.0f/b, rob=1.0f/(1-b); m' = num * r (plain v_mul_f32).
//
// Brent cycle fast-forward (bit-exact): the trajectory is a deterministic
// function of m's bits. If m == anchor (an earlier value) while rows are
// still active, every future m repeats values those rows already missed ->
// they can never fire -> k += remaining iterations. This converts the
// absorbed trap column (..->1.0->0->0..., a 1-cycle) from a 4096-iteration
// serial tail into ~2*t_absorb iterations. -inf (divergent negative path)
// is likewise a 1-cycle. NaN never equals anchor -> falls through (NaN
// band-compares are false -> element exits normally, same as reference).
// ---------------------------------------------------------------------------
__global__ __launch_bounds__(256) void fire_kernel(
    const float* __restrict__ x, const float* __restrict__ bmap,
    const float* __restrict__ qini, const float* __restrict__ eps,
    float* __restrict__ kout)
{
    const int cc = blockIdx.x & 31;   // column chunk (32 chunks of 256)
    const int g  = blockIdx.x >> 5;   // row group   (32 groups of RPT)
    const int j  = cc * 256 + threadIdx.x;
    const int r0 = g * RPT;

    const float bv  = bmap[j];
    const float qv  = qini[j];
    const float ev  = eps[j];
    const float obv = 1.0f - bv;      // exact (Sterbenz)
    const float rb  = 1.0f / bv;      // hoisted IEEE f32 reciprocals (ref flavor)
    const float rob = 1.0f / obv;

    float lo[RPT], hi[RPT];
    int   k[RPT];
    #pragma unroll
    for (int r = 0; r < RPT; ++r) {
        const float xv = x[(size_t)(r0 + r) * NN + j];
        lo[r] = xv - ev;              // exact f32 subs, same bits as ref
        hi[r] = xv + ev;
        k[r]  = 1;
    }
    unsigned act = (qv != 0.0f) ? ((1u << RPT) - 1u) : 0u;

    float m      = qv;
    float anchor = qv;                // Brent anchor (m_0)
    int   window = 1, steps = 0;

    for (int it = 0; act && it < MAX_ITERS; ++it) {
        const bool lt = (m < bv);
        m = (lt ? m : (1.0f - m)) * (lt ? rb : rob);   // reference flavor

        const bool cyc = (m == anchor);
        if (++steps == window) { anchor = m; window <<= 1; steps = 0; }

        #pragma unroll
        for (int r = 0; r < RPT; ++r) {
            const bool a = (act >> r) & 1u;
            const bool o = (m < lo[r]) || (m > hi[r]);
            k[r] += (a && o) ? 1 : 0;
            if (a && !o) act &= ~(1u << r);
        }

        if (cyc && act) {             // periodic & still active -> never fires
            #pragma unroll
            for (int r = 0; r < RPT; ++r)
                if ((act >> r) & 1u) k[r] += MAX_ITERS - 1 - it;
            break;
        }
    }

    #pragma unroll
    for (int r = 0; r < RPT; ++r)
        kout[(size_t)(r0 + r) * NN + j] = (float)k[r];
}

// ---------------------------------------------------------------------------
// Norm kernel: blocks 0..255 -> ||k[i]||, blocks 256..355 -> ||M[c]||.
// f64 accumulation (cheap, removes drift risk). norms[row]=max(sqrt,1e-8).
// ---------------------------------------------------------------------------
__global__ __launch_bounds__(256) void norm_kernel(
    const float* __restrict__ k, const float* __restrict__ M,
    float* __restrict__ norms)
{
    __shared__ double red[4];
    const int row = blockIdx.x;
    const float* src = (row < BB) ? (k + (size_t)row * NN)
                                  : (M + (size_t)(row - BB) * NN);
    double s = 0.0;
    for (int j = threadIdx.x * 4; j < NN; j += 1024) {
        const float4 v = *(const float4*)(src + j);
        s += (double)v.x * v.x + (double)v.y * v.y
           + (double)v.z * v.z + (double)v.w * v.w;
    }
    #pragma unroll
    for (int off = 32; off; off >>= 1) s += __shfl_down(s, off, 64);
    const int wid = threadIdx.x >> 6, lane = threadIdx.x & 63;
    if (lane == 0) red[wid] = s;
    __syncthreads();
    if (threadIdx.x == 0)
        norms[row] = fmaxf((float)sqrt(red[0] + red[1] + red[2] + red[3]), 1e-8f);
}

// ---------------------------------------------------------------------------
// Logits kernel: block = (row-pair, class-half). k rows held in registers
// (8 float4/row/thread, coalesced), M streamed (L2-resident, 3.2 MB).
// ---------------------------------------------------------------------------
__global__ __launch_bounds__(256) void logits_kernel(
    const float* __restrict__ k, const float* __restrict__ M,
    const float* __restrict__ norms, float* __restrict__ out)
{
    __shared__ float red0[4], red1[4];
    const int rp = blockIdx.x >> 1;       // 0..127
    const int ch = blockIdx.x & 1;        // 0..1
    const int i0 = rp * 2, i1 = i0 + 1;
    const int tid = threadIdx.x;

    float4 k0[8], k1[8];
    #pragma unroll
    for (int s = 0; s < 8; ++s) {
        k0[s] = *(const float4*)(k + (size_t)i0 * NN + s * 1024 + tid * 4);
        k1[s] = *(const float4*)(k + (size_t)i1 * NN + s * 1024 + tid * 4);
    }
    const float rn0 = norms[i0];
    const float rn1 = norms[i1];

    for (int c = ch * 50; c < ch * 50 + 50; ++c) {
        const float4* Mp = (const float4*)(M + (size_t)c * NN);
        float a0 = 0.0f, a1 = 0.0f;
        #pragma unroll
        for (int s = 0; s < 8; ++s) {
            const float4 mv = Mp[s * 256 + tid];
            a0 += k0[s].x * mv.x + k0[s].y * mv.y + k0[s].z * mv.z + k0[s].w * mv.w;
            a1 += k1[s].x * mv.x + k1[s].y * mv.y + k1[s].z * mv.z + k1[s].w * mv.w;
        }
        #pragma unroll
        for (int off = 32; off; off >>= 1) {
            a0 += __shfl_down(a0, off, 64);
            a1 += __shfl_down(a1, off, 64);
        }
        const int wid = tid >> 6, lane = tid & 63;
        if (lane == 0) { red0[wid] = a0; red1[wid] = a1; }
        __syncthreads();
        if (tid == 0) {
            const float d0 = red0[0] + red0[1] + red0[2] + red0[3];
            const float d1 = red1[0] + red1[1] + red1[2] + red1[3];
            const float mn = norms[BB + c];
            out[(size_t)i0 * CC + c] = d0 / (rn0 * mn);
            out[(size_t)i1 * CC + c] = d1 / (rn1 * mn);
        }
        __syncthreads();
    }
}

// ===========================================================================
// FALLBACK: round-10 fused kernel, verbatim (proven green at 569 us),
// used only if ws_size is too small for the k matrix.
// ===========================================================================
__global__ __launch_bounds__(256) void gls_fused_kernel(
    const float* __restrict__ x, const float* __restrict__ bmap,
    const float* __restrict__ qini, const float* __restrict__ eps,
    const float* __restrict__ M, float* __restrict__ out)
{
    __shared__ float k_lds[NN];
    __shared__ double redsh[4];

    const int i   = blockIdx.x;
    const int tid = threadIdx.x;
    const int wid = tid >> 6, lane = tid & 63;

    double sumsq = 0.0;
    for (int s = 0; s < 32; ++s) {
        const int j = tid + 256 * s;
        const float bv = bmap[j];
        const float qv = qini[j];
        const float ev = eps[j];
        const float xv = x[(size_t)i * NN + j];
        const float lov = xv - ev;
        const float hiv = xv + ev;
        const float obv = 1.0f - bv;
        const float rb  = 1.0f / bv;
        const float rob = 1.0f / obv;

        float m  = qv;
        float kk = 1.0f;
        bool  a  = (qv != 0.0f);
        for (int it = 0; a && it < MAX_ITERS; ++it) {
            const bool  lt  = (m < bv);
            const float num = lt ? m  : (1.0f - m);
            const float r   = lt ? rb : rob;
            m = num * r;
            a = (m < lov) || (m > hiv);
            kk += a ? 1.0f : 0.0f;
        }
        k_lds[j] = kk;
        sumsq += (double)kk * (double)kk;
    }

    #pragma unroll
    for (int off = 32; off; off >>= 1) sumsq += __shfl_down(sumsq, off, 64);
    if (lane == 0) redsh[wid] = sumsq;
    __syncthreads();
    const double rn = fmax(sqrt(redsh[0] + redsh[1] + redsh[2] + redsh[3]), 1e-8);

    for (int cc2 = 0; cc2 < 25; ++cc2) {
        const int c = wid * 25 + cc2;
        const float4* Mp = (const float4*)(M + (size_t)c * NN);
        double dot = 0.0, msq = 0.0;
        #pragma unroll 4
        for (int s = 0; s < 32; ++s) {
            const float4 mv = Mp[lane + 64 * s];
            const float4 kv = *(const float4*)(&k_lds[4 * (lane + 64 * s)]);
            dot += (double)kv.x * (double)mv.x + (double)kv.y * (double)mv.y
                 + (double)kv.z * (double)mv.z + (double)kv.w * (double)mv.w;
            msq += (double)mv.x * (double)mv.x + (double)mv.y * (double)mv.y
                 + (double)mv.z * (double)mv.z + (double)mv.w * (double)mv.w;
        }
        #pragma unroll
        for (int off = 32; off; off >>= 1) {
            dot += __shfl_down(dot, off, 64);
            msq += __shfl_down(msq, off, 64);
        }
        if (lane == 0) {
            const double mn = fmax(sqrt(msq), 1e-8);
            out[(size_t)i * CC + c] = (float)(dot / (rn * mn));
        }
    }
}

// ---------------------------------------------------------------------------
extern "C" void kernel_launch(void* const* d_in, const int* in_sizes, int n_in,
                              void* d_out, int out_size, void* d_ws, size_t ws_size,
                              hipStream_t stream) {
    const float* x = (const float*)d_in[0];  // (256, 8192)
    const float* b = (const float*)d_in[1];  // (8192,)
    const float* q = (const float*)d_in[2];  // (8192,)
    const float* e = (const float*)d_in[3];  // (8192,)
    const float* M = (const float*)d_in[4];  // (100, 8192)
    float* out = (float*)d_out;              // (256, 100)

    const size_t need = (size_t)BB * NN * sizeof(float) + (BB + CC) * sizeof(float);
    if (ws_size >= need) {
        float* kbuf  = (float*)d_ws;
        float* norms = kbuf + (size_t)BB * NN;
        fire_kernel<<<dim3(1024), dim3(256), 0, stream>>>(x, b, q, e, kbuf);
        norm_kernel<<<dim3(BB + CC), dim3(256), 0, stream>>>(kbuf, M, norms);
        logits_kernel<<<dim3(256), dim3(256), 0, stream>>>(kbuf, M, norms, out);
    } else {
        gls_fused_kernel<<<dim3(BB), dim3(256), 0, stream>>>(x, b, q, e, M, out);
    }
}